// Round 2
// baseline (5396.563 us; speedup 1.0000x reference)
//
#include <hip/hip_runtime.h>
#include <math.h>

// ---------------- problem constants ----------------
#define SEQ    1000
#define BATCH  256
#define INDIM  700
#define H1     256
#define H2     256
#define OUTD   20
#define W1COLS 956   // IN + H1
#define W2COLS 512   // H1 + H2

// ---------------- ws layout (float offsets) ----------------
#define OFF_W1FFT  0                         // 700*256 = 179200
#define OFF_W1RT   179200                    // 256*256 = 65536
#define OFF_W2T    244736                    // 512*256 = 131072
#define OFF_WOUTT  375808                    // 256*20  = 5120
#define OFF_PARAMS 380928                    // 1044 (alpha1,rho1,alpha2,rho2,ao)
#define OFF_STATE  381984                    // 256*1600 = 409600
#define OFF_CUR    791584                    // chunk buffer: Tc*256*256
#define STATE_STRIDE 1600

// ------------------------------------------------------------------
// prep: transpose weights, compute decay constants
// ------------------------------------------------------------------
__global__ __launch_bounds__(256) void prep_kernel(
    const float* __restrict__ W1, const float* __restrict__ W2,
    const float* __restrict__ Wout,
    const float* __restrict__ tau_m1, const float* __restrict__ tau_adp1,
    const float* __restrict__ tau_m2, const float* __restrict__ tau_adp2,
    const float* __restrict__ tau_out,
    float* __restrict__ ws)
{
    const int total = 179200 + 65536 + 131072 + 5120 + 1044; // 381972
    for (int idx = blockIdx.x * 256 + threadIdx.x; idx < total;
         idx += gridDim.x * 256) {
        if (idx < 179200) {                       // W1ffT[k*256+h] = W1[h][k]
            int k = idx >> 8, h = idx & 255;
            ws[OFF_W1FFT + idx] = W1[h * W1COLS + k];
        } else if (idx < 244736) {                // W1rT[j*256+h] = W1[h][700+j]
            int r = idx - 179200;
            int j = r >> 8, h = r & 255;
            ws[OFF_W1RT + r] = W1[h * W1COLS + 700 + j];
        } else if (idx < 375808) {                // W2T[j*256+h] = W2[h][j]
            int r = idx - 244736;
            int j = r >> 8, h = r & 255;
            ws[OFF_W2T + r] = W2[h * W2COLS + j];
        } else if (idx < 380928) {                // WoutT[j*20+o] = Wout[o][j]
            int r = idx - 375808;
            int j = r / 20, o = r % 20;
            ws[OFF_WOUTT + r] = Wout[o * 256 + j];
        } else {                                  // params
            int r = idx - 380928;                 // 0..1043
            float v = 0.f;
            if (r < 256)       { float q = -1.0f / tau_m1[r];        v = (float)exp((double)q); }
            else if (r < 512)  { float q = -1.0f / tau_adp1[r-256];  v = (float)exp((double)q); }
            else if (r < 768)  { float q = -1.0f / tau_m2[r-512];    v = (float)exp((double)q); }
            else if (r < 1024) { float q = -1.0f / tau_adp2[r-768];  v = (float)exp((double)q); }
            else               { float q = -1.0f / tau_out[r-1024];  v = (float)exp((double)q); }
            ws[OFF_PARAMS + r] = v;
        }
    }
}

// ------------------------------------------------------------------
// gemm_ff: cur[m][h] = sum_k x[m][k] * W1ffT[k][h]   (M x 700) @ (700 x 256)
// tile: 128 rows x 256 cols per block, BK=16, 256 threads, 8x16 per thread.
// Register double-buffer: next K-tile global loads issue before compute.
// ------------------------------------------------------------------
__global__ __launch_bounds__(256, 2) void gemm_ff(
    const float* __restrict__ x, const float* __restrict__ Bm,
    float* __restrict__ cur)
{
    __shared__ __align__(16) float As[16][128];
    __shared__ __align__(16) float Bs[16][256];
    const int tid = threadIdx.x;
    const int m0  = blockIdx.x * 128;
    const int r0  = (tid >> 4) << 3;      // rows r0..r0+7
    const int cb  = (tid & 15) << 2;      // cols cb + 64*j

    const int ar = tid >> 1;              // A load: row (0..127)
    const int ak = (tid & 1) << 3;        // A load: k base (0 or 8)
    const int bk = tid >> 4;              // B load: k row (0..15)
    const int bc = (tid & 15) << 4;       // B load: col base (64B chunks)

    float4 acc[8][4];
    #pragma unroll
    for (int i = 0; i < 8; ++i)
        #pragma unroll
        for (int j = 0; j < 4; ++j)
            acc[i][j] = make_float4(0.f, 0.f, 0.f, 0.f);

    const float* xrow = x + (size_t)(m0 + ar) * INDIM;

    // prefetch k0 = 0 into registers
    float4 aP0 = *(const float4*)&xrow[ak];
    float4 aP1 = *(const float4*)&xrow[ak + 4];
    float4 bP0, bP1, bP2, bP3;
    {
        const float* bp = Bm + (size_t)bk * 256 + bc;
        bP0 = *(const float4*)(bp);
        bP1 = *(const float4*)(bp + 4);
        bP2 = *(const float4*)(bp + 8);
        bP3 = *(const float4*)(bp + 12);
    }

    for (int k0 = 0; k0 < INDIM; k0 += 16) {
        __syncthreads();                  // prev compute done reading LDS
        As[ak+0][ar] = aP0.x; As[ak+1][ar] = aP0.y;
        As[ak+2][ar] = aP0.z; As[ak+3][ar] = aP0.w;
        As[ak+4][ar] = aP1.x; As[ak+5][ar] = aP1.y;
        As[ak+6][ar] = aP1.z; As[ak+7][ar] = aP1.w;
        *(float4*)&Bs[bk][bc]      = bP0;
        *(float4*)&Bs[bk][bc + 4]  = bP1;
        *(float4*)&Bs[bk][bc + 8]  = bP2;
        *(float4*)&Bs[bk][bc + 12] = bP3;
        __syncthreads();

        const int kn = k0 + 16;
        if (kn < INDIM) {                 // issue next-tile loads before compute
            const int ka = kn + ak;
            aP0 = (ka     < INDIM) ? *(const float4*)&xrow[ka]
                                   : make_float4(0.f,0.f,0.f,0.f);
            aP1 = (ka + 4 < INDIM) ? *(const float4*)&xrow[ka + 4]
                                   : make_float4(0.f,0.f,0.f,0.f);
            if (kn + bk < INDIM) {
                const float* bp = Bm + (size_t)(kn + bk) * 256 + bc;
                bP0 = *(const float4*)(bp);
                bP1 = *(const float4*)(bp + 4);
                bP2 = *(const float4*)(bp + 8);
                bP3 = *(const float4*)(bp + 12);
            } else {
                bP0 = bP1 = bP2 = bP3 = make_float4(0.f,0.f,0.f,0.f);
            }
        }

        #pragma unroll
        for (int kk = 0; kk < 16; ++kk) {
            float4 a0 = *(const float4*)&As[kk][r0];
            float4 a1 = *(const float4*)&As[kk][r0 + 4];
            float av[8] = {a0.x, a0.y, a0.z, a0.w, a1.x, a1.y, a1.z, a1.w};
            #pragma unroll
            for (int j = 0; j < 4; ++j) {
                float4 b4 = *(const float4*)&Bs[kk][cb + (j << 6)];
                #pragma unroll
                for (int i = 0; i < 8; ++i) {
                    acc[i][j].x += av[i] * b4.x;
                    acc[i][j].y += av[i] * b4.y;
                    acc[i][j].z += av[i] * b4.z;
                    acc[i][j].w += av[i] * b4.w;
                }
            }
        }
    }

    #pragma unroll
    for (int i = 0; i < 8; ++i)
        #pragma unroll
        for (int j = 0; j < 4; ++j)
            *(float4*)&cur[(size_t)(m0 + r0 + i) * 256 + cb + (j << 6)] = acc[i][j];
}

// ------------------------------------------------------------------
// sequential ALIF kernel — skewed pipeline + wave-split float4 gather.
//
// Gather restructure: each wave walks 1/4 of the active list and loads
// float4 rows covering ALL 256 h (lane l -> h=4l..4l+3); per-wave partials
// are reduced through LDS (pg1/pg2) at the existing barrier points.
// Wout gather uses each wave's own ballot bitmask (no act2 dependency),
// keeping 4 barriers/step.
//
// Invariant at top of iteration tt:
//   acc1      = ff(tt) + W1r-gather over z1_{tt-1}          (ready)
//   act2/n2   = active list of z2_{tt-1}                    (ready)
//   opart[]   = Wout partial sums over z2_{tt-1}            (ready, tt>0)
// ------------------------------------------------------------------
__global__ __launch_bounds__(256) void seq_kernel(
    const float* __restrict__ cur1ff,   // T x 256 x 256 (chunk-local)
    const float* __restrict__ W1rT,     // 256 x 256
    const float* __restrict__ W2T,      // 512 x 256
    const float* __restrict__ WoutT,    // 256 x 20
    const float* __restrict__ P,        // params
    float* __restrict__ state,
    float* __restrict__ out,
    int t0, int T)
{
    const int b = blockIdx.x;
    const int h = threadIdx.x;
    const int lane = h & 63, w = h >> 6;
    const int c4 = lane << 2;

    __shared__ int act1[256];
    __shared__ int act2[256];
    __shared__ unsigned long long wm1[4];
    __shared__ unsigned long long wm2[4];
    __shared__ float opart[128];                    // 4 waves x 32 slots
    __shared__ __align__(16) float pg1[1024];       // [4][256] wave partials
    __shared__ __align__(16) float pg2[1024];

    float* st = state + (size_t)b * STATE_STRIDE;

    const float al1 = P[h],        rho1 = P[256 + h];
    const float al2 = P[512 + h],  rho2 = P[768 + h];
    const float om_al1  = __fsub_rn(1.0f, al1);
    const float om_rho1 = __fsub_rn(1.0f, rho1);
    const float om_al2  = __fsub_rn(1.0f, al2);
    const float om_rho2 = __fsub_rn(1.0f, rho2);
    float ao = 0.f, om_ao = 0.f;
    if (h < OUTD) { ao = P[1024 + h]; om_ao = __fsub_rn(1.0f, ao); }

    float u1, a1, z1, u2, a2, z2, uo = 0.f;
    if (t0 == 0) {
        u1 = a1 = z1 = u2 = a2 = z2 = 0.f;
    } else {
        u1 = st[h];        a1 = st[256 + h];
        u2 = st[512 + h];  a2 = st[768 + h];
        z1 = st[1024 + h]; z2 = st[1280 + h];
        if (h < OUTD) uo = st[1536 + h];
    }

    // ---- prologue: build both lists from carried state ----
    int n1, n2;
    {
        unsigned long long b1m = __ballot(z1 > 0.5f);
        unsigned long long b2m = __ballot(z2 > 0.5f);
        if (lane == 0) { wm1[w] = b1m; wm2[w] = b2m; }
        __syncthreads();
        unsigned long long q0 = wm1[0], q1 = wm1[1], q2 = wm1[2], q3 = wm1[3];
        unsigned long long r0 = wm2[0], r1 = wm2[1], r2 = wm2[2], r3 = wm2[3];
        int base1 = 0, base2 = 0;
        if (w > 0) { base1 += __popcll(q0); base2 += __popcll(r0); }
        if (w > 1) { base1 += __popcll(q1); base2 += __popcll(r1); }
        if (w > 2) { base1 += __popcll(q2); base2 += __popcll(r2); }
        unsigned long long below = (1ull << lane) - 1ull;
        if (z1 > 0.5f) act1[base1 + __popcll(b1m & below)] = h;
        if (z2 > 0.5f) act2[base2 + __popcll(b2m & below)] = h;
        n1 = __popcll(q0) + __popcll(q1) + __popcll(q2) + __popcll(q3);
        n2 = __popcll(r0) + __popcll(r1) + __popcll(r2) + __popcll(r3);
        __syncthreads();
    }

    // ---- prologue wave-split gather: acc1 for local step 0 ----
    float acc1;
    {
        float4 p1 = make_float4(0.f, 0.f, 0.f, 0.f);
        for (int i = w; i < n1; i += 4) {
            float4 v = *(const float4*)(W1rT + (act1[i] << 8) + c4);
            p1.x += v.x; p1.y += v.y; p1.z += v.z; p1.w += v.w;
        }
        *(float4*)&pg1[(w << 8) + c4] = p1;
        __syncthreads();
        acc1 = cur1ff[((size_t)b << 8) + h]
             + ((pg1[h] + pg1[256 + h]) + (pg1[512 + h] + pg1[768 + h]));
    }

    for (int tt = 0; tt < T; ++tt) {
        // ---- phase A: prefetch next ff; layer1 update; ballot ----
        float ffn = 0.f;
        if (tt + 1 < T)
            ffn = cur1ff[((size_t)(tt + 1) * 256 + b) * 256 + h];

        a1 = __fadd_rn(__fmul_rn(rho1, a1), __fmul_rn(om_rho1, z1));
        float th1 = __fadd_rn(0.01f, __fmul_rn(1.8f, a1));
        u1 = __fsub_rn(__fadd_rn(__fmul_rn(al1, u1), __fmul_rn(om_al1, acc1)),
                       __fmul_rn(z1, th1));
        z1 = (__fsub_rn(u1, th1) > 0.0f) ? 1.0f : 0.0f;
        unsigned long long bm1 = __ballot(z1 > 0.5f);
        if (lane == 0) wm1[w] = bm1;

        __syncthreads();                          // BAR1

        // ---- phase B: uo finalize (prev step) + act1 build ----
        if (tt > 0 && h < OUTD) {
            float s = ((opart[h] + opart[32 + h]) + (opart[64 + h] + opart[96 + h]));
            uo = __fadd_rn(__fmul_rn(ao, uo), __fmul_rn(om_ao, s));
            int tg = t0 + tt - 1;
            if (tg >= 1)
                out[((size_t)(tg - 1) * BATCH + b) * OUTD + h] = uo;
        }
        {
            unsigned long long q0 = wm1[0], q1 = wm1[1], q2 = wm1[2], q3 = wm1[3];
            int base = 0;
            if (w > 0) base += __popcll(q0);
            if (w > 1) base += __popcll(q1);
            if (w > 2) base += __popcll(q2);
            if (z1 > 0.5f)
                act1[base + __popcll(bm1 & ((1ull << lane) - 1ull))] = h;
            n1 = __popcll(q0) + __popcll(q1) + __popcll(q2) + __popcll(q3);
        }
        __syncthreads();                          // BAR2

        // ---- phase C: wave-split float4 gather (acc1_next + acc2) ----
        float4 p1 = make_float4(0.f, 0.f, 0.f, 0.f);
        float4 p2 = make_float4(0.f, 0.f, 0.f, 0.f);
        {
            int i = w;
            for (; i + 12 < n1; i += 16) {
                int j0 = act1[i], j1 = act1[i+4], j2 = act1[i+8], j3 = act1[i+12];
                float4 a0 = *(const float4*)(W1rT + (j0 << 8) + c4);
                float4 a1v = *(const float4*)(W1rT + (j1 << 8) + c4);
                float4 a2v = *(const float4*)(W1rT + (j2 << 8) + c4);
                float4 a3v = *(const float4*)(W1rT + (j3 << 8) + c4);
                float4 b0 = *(const float4*)(W2T + (j0 << 8) + c4);
                float4 b1 = *(const float4*)(W2T + (j1 << 8) + c4);
                float4 b2 = *(const float4*)(W2T + (j2 << 8) + c4);
                float4 b3 = *(const float4*)(W2T + (j3 << 8) + c4);
                p1.x += (a0.x + a1v.x) + (a2v.x + a3v.x);
                p1.y += (a0.y + a1v.y) + (a2v.y + a3v.y);
                p1.z += (a0.z + a1v.z) + (a2v.z + a3v.z);
                p1.w += (a0.w + a1v.w) + (a2v.w + a3v.w);
                p2.x += (b0.x + b1.x) + (b2.x + b3.x);
                p2.y += (b0.y + b1.y) + (b2.y + b3.y);
                p2.z += (b0.z + b1.z) + (b2.z + b3.z);
                p2.w += (b0.w + b1.w) + (b2.w + b3.w);
            }
            for (; i < n1; i += 4) {
                int j = act1[i];
                float4 a0 = *(const float4*)(W1rT + (j << 8) + c4);
                float4 b0 = *(const float4*)(W2T + (j << 8) + c4);
                p1.x += a0.x; p1.y += a0.y; p1.z += a0.z; p1.w += a0.w;
                p2.x += b0.x; p2.y += b0.y; p2.z += b0.z; p2.w += b0.w;
            }
            for (i = w; i + 12 < n2; i += 16) {
                int j0 = act2[i], j1 = act2[i+4], j2 = act2[i+8], j3 = act2[i+12];
                float4 b0 = *(const float4*)(W2T + ((256 + j0) << 8) + c4);
                float4 b1 = *(const float4*)(W2T + ((256 + j1) << 8) + c4);
                float4 b2 = *(const float4*)(W2T + ((256 + j2) << 8) + c4);
                float4 b3 = *(const float4*)(W2T + ((256 + j3) << 8) + c4);
                p2.x += (b0.x + b1.x) + (b2.x + b3.x);
                p2.y += (b0.y + b1.y) + (b2.y + b3.y);
                p2.z += (b0.z + b1.z) + (b2.z + b3.z);
                p2.w += (b0.w + b1.w) + (b2.w + b3.w);
            }
            for (; i < n2; i += 4) {
                float4 b0 = *(const float4*)(W2T + ((256 + act2[i]) << 8) + c4);
                p2.x += b0.x; p2.y += b0.y; p2.z += b0.z; p2.w += b0.w;
            }
        }
        *(float4*)&pg1[(w << 8) + c4] = p1;
        *(float4*)&pg2[(w << 8) + c4] = p2;
        __syncthreads();                          // BAR3

        // ---- phase D: reduce partials; layer2 update; ballot; Wout ----
        float acc2 = (pg2[h] + pg2[256 + h]) + (pg2[512 + h] + pg2[768 + h]);
        acc1 = ffn + ((pg1[h] + pg1[256 + h]) + (pg1[512 + h] + pg1[768 + h]));

        a2 = __fadd_rn(__fmul_rn(rho2, a2), __fmul_rn(om_rho2, z2));
        float th2 = __fadd_rn(0.01f, __fmul_rn(1.8f, a2));
        u2 = __fsub_rn(__fadd_rn(__fmul_rn(al2, u2), __fmul_rn(om_al2, acc2)),
                       __fmul_rn(z2, th2));
        z2 = (__fsub_rn(u2, th2) > 0.0f) ? 1.0f : 0.0f;
        unsigned long long bm2 = __ballot(z2 > 0.5f);
        if (lane == 0) wm2[w] = bm2;

        // Wout partials from own-wave ballot bitmask (no act2 dependency)
        if (lane < OUTD) {
            unsigned long long m = bm2;
            float p = 0.f;
            while (m) {
                int bit = (int)__builtin_ctzll(m);
                m &= m - 1ull;
                p += WoutT[((w << 6) + bit) * OUTD + lane];
            }
            opart[(w << 5) + lane] = p;
        }
        __syncthreads();                          // BAR4

        // ---- phase E: act2 build (for next step's gather) ----
        {
            unsigned long long q0 = wm2[0], q1 = wm2[1], q2 = wm2[2], q3 = wm2[3];
            int base = 0;
            if (w > 0) base += __popcll(q0);
            if (w > 1) base += __popcll(q1);
            if (w > 2) base += __popcll(q2);
            if (z2 > 0.5f)
                act2[base + __popcll(bm2 & ((1ull << lane) - 1ull))] = h;
            n2 = __popcll(q0) + __popcll(q1) + __popcll(q2) + __popcll(q3);
        }
    }

    // ---- epilogue: finalize uo for global step (t0+T-1) ----
    __syncthreads();
    if (h < OUTD) {
        float s = ((opart[h] + opart[32 + h]) + (opart[64 + h] + opart[96 + h]));
        uo = __fadd_rn(__fmul_rn(ao, uo), __fmul_rn(om_ao, s));
        int tg = t0 + T - 1;
        if (tg >= 1)
            out[((size_t)(tg - 1) * BATCH + b) * OUTD + h] = uo;
    }

    // persist state for next chunk
    st[h]        = u1;  st[256 + h]  = a1;
    st[512 + h]  = u2;  st[768 + h]  = a2;
    st[1024 + h] = z1;  st[1280 + h] = z2;
    if (h < OUTD) st[1536 + h] = uo;
}

// ------------------------------------------------------------------
extern "C" void kernel_launch(void* const* d_in, const int* in_sizes, int n_in,
                              void* d_out, int out_size, void* d_ws, size_t ws_size,
                              hipStream_t stream)
{
    const float* x        = (const float*)d_in[0];
    const float* W1       = (const float*)d_in[1];
    const float* tau_m1   = (const float*)d_in[2];
    const float* tau_adp1 = (const float*)d_in[3];
    const float* W2       = (const float*)d_in[4];
    const float* tau_m2   = (const float*)d_in[5];
    const float* tau_adp2 = (const float*)d_in[6];
    const float* Wout     = (const float*)d_in[7];
    const float* tau_out  = (const float*)d_in[8];
    float* out = (float*)d_out;
    float* ws  = (float*)d_ws;

    prep_kernel<<<512, 256, 0, stream>>>(W1, W2, Wout, tau_m1, tau_adp1,
                                         tau_m2, tau_adp2, tau_out, ws);

    size_t ws_floats = ws_size / 4;
    size_t cap = (ws_floats > (size_t)OFF_CUR) ? ws_floats - (size_t)OFF_CUR : 0;
    int Tc = (int)((cap / (BATCH * H1) < (size_t)SEQ) ? cap / (BATCH * H1) : (size_t)SEQ);
    if (Tc < 1) return;  // workspace too small — will fail loudly

    int t0 = 0;
    while (t0 < SEQ) {
        int T = (SEQ - t0 < Tc) ? (SEQ - t0) : Tc;
        gemm_ff<<<dim3(T * (BATCH / 128)), 256, 0, stream>>>(
            x + (size_t)t0 * BATCH * INDIM, ws + OFF_W1FFT, ws + OFF_CUR);
        seq_kernel<<<dim3(BATCH), 256, 0, stream>>>(
            ws + OFF_CUR, ws + OFF_W1RT, ws + OFF_W2T, ws + OFF_WOUTT,
            ws + OFF_PARAMS, ws + OFF_STATE, out, t0, T);
        t0 += T;
    }
}

// Round 4
// 3203.381 us; speedup vs baseline: 1.6846x; 1.6846x over previous
//
#include <hip/hip_runtime.h>
#include <math.h>

// ---------------- problem constants ----------------
#define SEQ    1000
#define BATCH  256
#define INDIM  700
#define H1     256
#define H2     256
#define OUTD   20
#define W1COLS 956   // IN + H1
#define W2COLS 512   // H1 + H2

// ---------------- ws layout (float offsets) ----------------
#define OFF_W1FFT  0                         // 700*256 = 179200
#define OFF_W1RT   179200                    // 256*256 = 65536
#define OFF_W2T    244736                    // 512*256 = 131072
#define OFF_WOUTT  375808                    // 256*20  = 5120
#define OFF_PARAMS 380928                    // 1044 (alpha1,rho1,alpha2,rho2,ao)
#define OFF_STATE  381984                    // 256*1600 = 409600
#define OFF_CUR    791584                    // chunk buffer: Tc*256*256
#define STATE_STRIDE 1600

// ------------------------------------------------------------------
// prep: transpose weights, compute decay constants
// ------------------------------------------------------------------
__global__ __launch_bounds__(256) void prep_kernel(
    const float* __restrict__ W1, const float* __restrict__ W2,
    const float* __restrict__ Wout,
    const float* __restrict__ tau_m1, const float* __restrict__ tau_adp1,
    const float* __restrict__ tau_m2, const float* __restrict__ tau_adp2,
    const float* __restrict__ tau_out,
    float* __restrict__ ws)
{
    const int total = 179200 + 65536 + 131072 + 5120 + 1044; // 381972
    for (int idx = blockIdx.x * 256 + threadIdx.x; idx < total;
         idx += gridDim.x * 256) {
        if (idx < 179200) {                       // W1ffT[k*256+h] = W1[h][k]
            int k = idx >> 8, h = idx & 255;
            ws[OFF_W1FFT + idx] = W1[h * W1COLS + k];
        } else if (idx < 244736) {                // W1rT[j*256+h] = W1[h][700+j]
            int r = idx - 179200;
            int j = r >> 8, h = r & 255;
            ws[OFF_W1RT + r] = W1[h * W1COLS + 700 + j];
        } else if (idx < 375808) {                // W2T[j*256+h] = W2[h][j]
            int r = idx - 244736;
            int j = r >> 8, h = r & 255;
            ws[OFF_W2T + r] = W2[h * W2COLS + j];
        } else if (idx < 380928) {                // WoutT[j*20+o] = Wout[o][j]
            int r = idx - 375808;
            int j = r / 20, o = r % 20;
            ws[OFF_WOUTT + r] = Wout[o * 256 + j];
        } else {                                  // params
            int r = idx - 380928;                 // 0..1043
            float v = 0.f;
            if (r < 256)       { float q = -1.0f / tau_m1[r];        v = (float)exp((double)q); }
            else if (r < 512)  { float q = -1.0f / tau_adp1[r-256];  v = (float)exp((double)q); }
            else if (r < 768)  { float q = -1.0f / tau_m2[r-512];    v = (float)exp((double)q); }
            else if (r < 1024) { float q = -1.0f / tau_adp2[r-768];  v = (float)exp((double)q); }
            else               { float q = -1.0f / tau_out[r-1024];  v = (float)exp((double)q); }
            ws[OFF_PARAMS + r] = v;
        }
    }
}

// ------------------------------------------------------------------
// gemm_ff: cur[m][h] = sum_k x[m][k] * W1ffT[k][h]   (M x 700) @ (700 x 256)
// tile: 64 rows x 256 cols per block, BK=16, 256 threads, 4x16 per thread.
// Register double-buffer: next K-tile loads issue before the compute phase.
// VGPR budget: 64 acc + 20 prefetch + addressing ~ 110 (no spill).
// ------------------------------------------------------------------
__global__ __launch_bounds__(256) void gemm_ff(
    const float* __restrict__ x, const float* __restrict__ Bm,
    float* __restrict__ cur)
{
    __shared__ __align__(16) float As[16][68];    // pad 64->68: aligned + 2-way max
    __shared__ __align__(16) float Bs[16][256];

    const int tid = threadIdx.x;
    const int m0  = blockIdx.x * 64;

    // output mapping: rows r0..r0+3, cols cb + 64*j
    const int r0 = (tid >> 4) << 2;
    const int cb = (tid & 15) << 2;

    // A staging: thread -> row ar, k-quad aq (k = aq..aq+3)
    const int ar = tid >> 2;
    const int aq = (tid & 3) << 2;

    // B staging: wave quarter -> 4 rows, lane-consecutive float4 (dense 1KB)
    const int bw = tid >> 6;              // 0..3 -> rows bw*4+j
    const int bl = (tid & 63) << 2;       // col (lane-consecutive)

    float4 acc[4][4];
    #pragma unroll
    for (int i = 0; i < 4; ++i)
        #pragma unroll
        for (int j = 0; j < 4; ++j)
            acc[i][j] = make_float4(0.f, 0.f, 0.f, 0.f);

    const float* xrow = x + (size_t)(m0 + ar) * INDIM;

    // prefetch K-tile 0
    float4 aP = *(const float4*)&xrow[aq];
    float4 bP[4];
    #pragma unroll
    for (int j = 0; j < 4; ++j)
        bP[j] = *(const float4*)&Bm[(size_t)(bw * 4 + j) * 256 + bl];

    for (int k0 = 0; k0 < INDIM; k0 += 16) {
        __syncthreads();                  // previous compute done reading LDS
        As[aq + 0][ar] = aP.x;
        As[aq + 1][ar] = aP.y;
        As[aq + 2][ar] = aP.z;
        As[aq + 3][ar] = aP.w;
        #pragma unroll
        for (int j = 0; j < 4; ++j)
            *(float4*)&Bs[bw * 4 + j][bl] = bP[j];
        __syncthreads();

        const int kn = k0 + 16;
        if (kn < INDIM) {                 // issue next-tile loads before compute
            aP = (kn + aq + 4 <= INDIM) ? *(const float4*)&xrow[kn + aq]
                                        : make_float4(0.f, 0.f, 0.f, 0.f);
            #pragma unroll
            for (int j = 0; j < 4; ++j) {
                int kr = kn + bw * 4 + j;
                bP[j] = (kr < INDIM) ? *(const float4*)&Bm[(size_t)kr * 256 + bl]
                                     : make_float4(0.f, 0.f, 0.f, 0.f);
            }
        }

        #pragma unroll
        for (int kk = 0; kk < 16; ++kk) {
            float4 a4 = *(const float4*)&As[kk][r0];
            float av[4] = {a4.x, a4.y, a4.z, a4.w};
            #pragma unroll
            for (int j = 0; j < 4; ++j) {
                float4 b4 = *(const float4*)&Bs[kk][cb + (j << 6)];
                #pragma unroll
                for (int i = 0; i < 4; ++i) {
                    acc[i][j].x += av[i] * b4.x;
                    acc[i][j].y += av[i] * b4.y;
                    acc[i][j].z += av[i] * b4.z;
                    acc[i][j].w += av[i] * b4.w;
                }
            }
        }
    }

    #pragma unroll
    for (int i = 0; i < 4; ++i)
        #pragma unroll
        for (int j = 0; j < 4; ++j)
            *(float4*)&cur[(size_t)(m0 + r0 + i) * 256 + cb + (j << 6)] = acc[i][j];
}

// ------------------------------------------------------------------
// sequential ALIF kernel — skewed pipeline + wave-split float4 gather.
// (unchanged from round 2 — measured ~1.8 ms, passed)
// ------------------------------------------------------------------
__global__ __launch_bounds__(256) void seq_kernel(
    const float* __restrict__ cur1ff,   // T x 256 x 256 (chunk-local)
    const float* __restrict__ W1rT,     // 256 x 256
    const float* __restrict__ W2T,      // 512 x 256
    const float* __restrict__ WoutT,    // 256 x 20
    const float* __restrict__ P,        // params
    float* __restrict__ state,
    float* __restrict__ out,
    int t0, int T)
{
    const int b = blockIdx.x;
    const int h = threadIdx.x;
    const int lane = h & 63, w = h >> 6;
    const int c4 = lane << 2;

    __shared__ int act1[256];
    __shared__ int act2[256];
    __shared__ unsigned long long wm1[4];
    __shared__ unsigned long long wm2[4];
    __shared__ float opart[128];                    // 4 waves x 32 slots
    __shared__ __align__(16) float pg1[1024];       // [4][256] wave partials
    __shared__ __align__(16) float pg2[1024];

    float* st = state + (size_t)b * STATE_STRIDE;

    const float al1 = P[h],        rho1 = P[256 + h];
    const float al2 = P[512 + h],  rho2 = P[768 + h];
    const float om_al1  = __fsub_rn(1.0f, al1);
    const float om_rho1 = __fsub_rn(1.0f, rho1);
    const float om_al2  = __fsub_rn(1.0f, al2);
    const float om_rho2 = __fsub_rn(1.0f, rho2);
    float ao = 0.f, om_ao = 0.f;
    if (h < OUTD) { ao = P[1024 + h]; om_ao = __fsub_rn(1.0f, ao); }

    float u1, a1, z1, u2, a2, z2, uo = 0.f;
    if (t0 == 0) {
        u1 = a1 = z1 = u2 = a2 = z2 = 0.f;
    } else {
        u1 = st[h];        a1 = st[256 + h];
        u2 = st[512 + h];  a2 = st[768 + h];
        z1 = st[1024 + h]; z2 = st[1280 + h];
        if (h < OUTD) uo = st[1536 + h];
    }

    // ---- prologue: build both lists from carried state ----
    int n1, n2;
    {
        unsigned long long b1m = __ballot(z1 > 0.5f);
        unsigned long long b2m = __ballot(z2 > 0.5f);
        if (lane == 0) { wm1[w] = b1m; wm2[w] = b2m; }
        __syncthreads();
        unsigned long long q0 = wm1[0], q1 = wm1[1], q2 = wm1[2], q3 = wm1[3];
        unsigned long long r0 = wm2[0], r1 = wm2[1], r2 = wm2[2], r3 = wm2[3];
        int base1 = 0, base2 = 0;
        if (w > 0) { base1 += __popcll(q0); base2 += __popcll(r0); }
        if (w > 1) { base1 += __popcll(q1); base2 += __popcll(r1); }
        if (w > 2) { base1 += __popcll(q2); base2 += __popcll(r2); }
        unsigned long long below = (1ull << lane) - 1ull;
        if (z1 > 0.5f) act1[base1 + __popcll(b1m & below)] = h;
        if (z2 > 0.5f) act2[base2 + __popcll(b2m & below)] = h;
        n1 = __popcll(q0) + __popcll(q1) + __popcll(q2) + __popcll(q3);
        n2 = __popcll(r0) + __popcll(r1) + __popcll(r2) + __popcll(r3);
        __syncthreads();
    }

    // ---- prologue wave-split gather: acc1 for local step 0 ----
    float acc1;
    {
        float4 p1 = make_float4(0.f, 0.f, 0.f, 0.f);
        for (int i = w; i < n1; i += 4) {
            float4 v = *(const float4*)(W1rT + (act1[i] << 8) + c4);
            p1.x += v.x; p1.y += v.y; p1.z += v.z; p1.w += v.w;
        }
        *(float4*)&pg1[(w << 8) + c4] = p1;
        __syncthreads();
        acc1 = cur1ff[((size_t)b << 8) + h]
             + ((pg1[h] + pg1[256 + h]) + (pg1[512 + h] + pg1[768 + h]));
    }

    for (int tt = 0; tt < T; ++tt) {
        // ---- phase A: prefetch next ff; layer1 update; ballot ----
        float ffn = 0.f;
        if (tt + 1 < T)
            ffn = cur1ff[((size_t)(tt + 1) * 256 + b) * 256 + h];

        a1 = __fadd_rn(__fmul_rn(rho1, a1), __fmul_rn(om_rho1, z1));
        float th1 = __fadd_rn(0.01f, __fmul_rn(1.8f, a1));
        u1 = __fsub_rn(__fadd_rn(__fmul_rn(al1, u1), __fmul_rn(om_al1, acc1)),
                       __fmul_rn(z1, th1));
        z1 = (__fsub_rn(u1, th1) > 0.0f) ? 1.0f : 0.0f;
        unsigned long long bm1 = __ballot(z1 > 0.5f);
        if (lane == 0) wm1[w] = bm1;

        __syncthreads();                          // BAR1

        // ---- phase B: uo finalize (prev step) + act1 build ----
        if (tt > 0 && h < OUTD) {
            float s = ((opart[h] + opart[32 + h]) + (opart[64 + h] + opart[96 + h]));
            uo = __fadd_rn(__fmul_rn(ao, uo), __fmul_rn(om_ao, s));
            int tg = t0 + tt - 1;
            if (tg >= 1)
                out[((size_t)(tg - 1) * BATCH + b) * OUTD + h] = uo;
        }
        {
            unsigned long long q0 = wm1[0], q1 = wm1[1], q2 = wm1[2], q3 = wm1[3];
            int base = 0;
            if (w > 0) base += __popcll(q0);
            if (w > 1) base += __popcll(q1);
            if (w > 2) base += __popcll(q2);
            if (z1 > 0.5f)
                act1[base + __popcll(bm1 & ((1ull << lane) - 1ull))] = h;
            n1 = __popcll(q0) + __popcll(q1) + __popcll(q2) + __popcll(q3);
        }
        __syncthreads();                          // BAR2

        // ---- phase C: wave-split float4 gather (acc1_next + acc2) ----
        float4 p1 = make_float4(0.f, 0.f, 0.f, 0.f);
        float4 p2 = make_float4(0.f, 0.f, 0.f, 0.f);
        {
            int i = w;
            for (; i + 12 < n1; i += 16) {
                int j0 = act1[i], j1 = act1[i+4], j2 = act1[i+8], j3 = act1[i+12];
                float4 a0 = *(const float4*)(W1rT + (j0 << 8) + c4);
                float4 a1v = *(const float4*)(W1rT + (j1 << 8) + c4);
                float4 a2v = *(const float4*)(W1rT + (j2 << 8) + c4);
                float4 a3v = *(const float4*)(W1rT + (j3 << 8) + c4);
                float4 b0 = *(const float4*)(W2T + (j0 << 8) + c4);
                float4 b1 = *(const float4*)(W2T + (j1 << 8) + c4);
                float4 b2 = *(const float4*)(W2T + (j2 << 8) + c4);
                float4 b3 = *(const float4*)(W2T + (j3 << 8) + c4);
                p1.x += (a0.x + a1v.x) + (a2v.x + a3v.x);
                p1.y += (a0.y + a1v.y) + (a2v.y + a3v.y);
                p1.z += (a0.z + a1v.z) + (a2v.z + a3v.z);
                p1.w += (a0.w + a1v.w) + (a2v.w + a3v.w);
                p2.x += (b0.x + b1.x) + (b2.x + b3.x);
                p2.y += (b0.y + b1.y) + (b2.y + b3.y);
                p2.z += (b0.z + b1.z) + (b2.z + b3.z);
                p2.w += (b0.w + b1.w) + (b2.w + b3.w);
            }
            for (; i < n1; i += 4) {
                int j = act1[i];
                float4 a0 = *(const float4*)(W1rT + (j << 8) + c4);
                float4 b0 = *(const float4*)(W2T + (j << 8) + c4);
                p1.x += a0.x; p1.y += a0.y; p1.z += a0.z; p1.w += a0.w;
                p2.x += b0.x; p2.y += b0.y; p2.z += b0.z; p2.w += b0.w;
            }
            for (i = w; i + 12 < n2; i += 16) {
                int j0 = act2[i], j1 = act2[i+4], j2 = act2[i+8], j3 = act2[i+12];
                float4 b0 = *(const float4*)(W2T + ((256 + j0) << 8) + c4);
                float4 b1 = *(const float4*)(W2T + ((256 + j1) << 8) + c4);
                float4 b2 = *(const float4*)(W2T + ((256 + j2) << 8) + c4);
                float4 b3 = *(const float4*)(W2T + ((256 + j3) << 8) + c4);
                p2.x += (b0.x + b1.x) + (b2.x + b3.x);
                p2.y += (b0.y + b1.y) + (b2.y + b3.y);
                p2.z += (b0.z + b1.z) + (b2.z + b3.z);
                p2.w += (b0.w + b1.w) + (b2.w + b3.w);
            }
            for (; i < n2; i += 4) {
                float4 b0 = *(const float4*)(W2T + ((256 + act2[i]) << 8) + c4);
                p2.x += b0.x; p2.y += b0.y; p2.z += b0.z; p2.w += b0.w;
            }
        }
        *(float4*)&pg1[(w << 8) + c4] = p1;
        *(float4*)&pg2[(w << 8) + c4] = p2;
        __syncthreads();                          // BAR3

        // ---- phase D: reduce partials; layer2 update; ballot; Wout ----
        float acc2 = (pg2[h] + pg2[256 + h]) + (pg2[512 + h] + pg2[768 + h]);
        acc1 = ffn + ((pg1[h] + pg1[256 + h]) + (pg1[512 + h] + pg1[768 + h]));

        a2 = __fadd_rn(__fmul_rn(rho2, a2), __fmul_rn(om_rho2, z2));
        float th2 = __fadd_rn(0.01f, __fmul_rn(1.8f, a2));
        u2 = __fsub_rn(__fadd_rn(__fmul_rn(al2, u2), __fmul_rn(om_al2, acc2)),
                       __fmul_rn(z2, th2));
        z2 = (__fsub_rn(u2, th2) > 0.0f) ? 1.0f : 0.0f;
        unsigned long long bm2 = __ballot(z2 > 0.5f);
        if (lane == 0) wm2[w] = bm2;

        // Wout partials from own-wave ballot bitmask (no act2 dependency)
        if (lane < OUTD) {
            unsigned long long m = bm2;
            float p = 0.f;
            while (m) {
                int bit = (int)__builtin_ctzll(m);
                m &= m - 1ull;
                p += WoutT[((w << 6) + bit) * OUTD + lane];
            }
            opart[(w << 5) + lane] = p;
        }
        __syncthreads();                          // BAR4

        // ---- phase E: act2 build (for next step's gather) ----
        {
            unsigned long long q0 = wm2[0], q1 = wm2[1], q2 = wm2[2], q3 = wm2[3];
            int base = 0;
            if (w > 0) base += __popcll(q0);
            if (w > 1) base += __popcll(q1);
            if (w > 2) base += __popcll(q2);
            if (z2 > 0.5f)
                act2[base + __popcll(bm2 & ((1ull << lane) - 1ull))] = h;
            n2 = __popcll(q0) + __popcll(q1) + __popcll(q2) + __popcll(q3);
        }
    }

    // ---- epilogue: finalize uo for global step (t0+T-1) ----
    __syncthreads();
    if (h < OUTD) {
        float s = ((opart[h] + opart[32 + h]) + (opart[64 + h] + opart[96 + h]));
        uo = __fadd_rn(__fmul_rn(ao, uo), __fmul_rn(om_ao, s));
        int tg = t0 + T - 1;
        if (tg >= 1)
            out[((size_t)(tg - 1) * BATCH + b) * OUTD + h] = uo;
    }

    // persist state for next chunk
    st[h]        = u1;  st[256 + h]  = a1;
    st[512 + h]  = u2;  st[768 + h]  = a2;
    st[1024 + h] = z1;  st[1280 + h] = z2;
    if (h < OUTD) st[1536 + h] = uo;
}

// ------------------------------------------------------------------
extern "C" void kernel_launch(void* const* d_in, const int* in_sizes, int n_in,
                              void* d_out, int out_size, void* d_ws, size_t ws_size,
                              hipStream_t stream)
{
    const float* x        = (const float*)d_in[0];
    const float* W1       = (const float*)d_in[1];
    const float* tau_m1   = (const float*)d_in[2];
    const float* tau_adp1 = (const float*)d_in[3];
    const float* W2       = (const float*)d_in[4];
    const float* tau_m2   = (const float*)d_in[5];
    const float* tau_adp2 = (const float*)d_in[6];
    const float* Wout     = (const float*)d_in[7];
    const float* tau_out  = (const float*)d_in[8];
    float* out = (float*)d_out;
    float* ws  = (float*)d_ws;

    prep_kernel<<<512, 256, 0, stream>>>(W1, W2, Wout, tau_m1, tau_adp1,
                                         tau_m2, tau_adp2, tau_out, ws);

    size_t ws_floats = ws_size / 4;
    size_t cap = (ws_floats > (size_t)OFF_CUR) ? ws_floats - (size_t)OFF_CUR : 0;
    int Tc = (int)((cap / (BATCH * H1) < (size_t)SEQ) ? cap / (BATCH * H1) : (size_t)SEQ);
    if (Tc < 1) return;  // workspace too small — will fail loudly

    int t0 = 0;
    while (t0 < SEQ) {
        int T = (SEQ - t0 < Tc) ? (SEQ - t0) : Tc;
        gemm_ff<<<dim3(T * (BATCH / 64)), 256, 0, stream>>>(
            x + (size_t)t0 * BATCH * INDIM, ws + OFF_W1FFT, ws + OFF_CUR);
        seq_kernel<<<dim3(BATCH), 256, 0, stream>>>(
            ws + OFF_CUR, ws + OFF_W1RT, ws + OFF_W2T, ws + OFF_WOUTT,
            ws + OFF_PARAMS, ws + OFF_STATE, out, t0, T);
        t0 += T;
    }
}